// Round 9
// baseline (188.330 us; speedup 1.0000x reference)
//
#include <hip/hip_runtime.h>

typedef unsigned short u16;
typedef unsigned int u32;
typedef unsigned long long u64;
typedef __attribute__((ext_vector_type(8))) short bf16x8;   // 8 bf16 (4 VGPRs)
typedef __attribute__((ext_vector_type(4))) float f32x4;    // MFMA C/D frag

#define MTOK 8192   // B*N tokens
#define KP   640    // K padded (588 -> 640 = 10*64)
#define CC   588
#define C3   1764
#define NH   14
#define SEQ  1024
#define HD   42
#define DP   64     // head-dim padded for QK^T K-loop
#define DV   48     // V^T rows: 42 real + ones row (42) + junk(43..47, unused cols)
#define SC2f 0.18033688011112042f  // 0.125 * log2(e)

static __device__ __forceinline__ u16 f2b(float f) {  // fp32 -> bf16 RNE
  unsigned u = __builtin_bit_cast(unsigned, f);
  u = (u + 0x7FFFu + ((u >> 16) & 1u)) >> 16;
  return (u16)u;
}

static __device__ __forceinline__ void gl_lds16(const void* g, void* l) {
  auto gp = (const unsigned int __attribute__((address_space(1)))*)((unsigned long long)g);
  auto lp = (unsigned int __attribute__((address_space(3)))*)((unsigned long long)l);
  __builtin_amdgcn_global_load_lds(gp, lp, 16, 0, 0);
}

// pack two fp32 -> (bf16(hi)<<16)|bf16(lo), round-half-up (1-ulp-equiv to RNE; softmax-norm safe)
static __device__ __forceinline__ u32 pk2(float lo, float hi) {
  u32 a = __builtin_bit_cast(u32, lo) + 0x8000u;
  u32 b = __builtin_bit_cast(u32, hi) + 0x8000u;
  return __builtin_amdgcn_perm(b, a, 0x07060302u);  // {hi16(b), hi16(a)}
}

// ---------------- im2col: x [8,3,448,448] f32 -> A [8192][640] bf16 (u32-paired stores) ----------------
// blocks 0..111 additionally: vT ones-row (d=42) + q/k d-pad zeros (d 40..63; gemm1 rewrites 40,41)
__global__ void im2col_k(const float* __restrict__ x, u16* __restrict__ A,
                         u16* __restrict__ vT, u16* __restrict__ qb, u16* __restrict__ kb) {
  int t = blockIdx.x;
  int b = t >> 10, pi = t & 1023, ph = pi >> 5, pw = pi & 31;
  const float* xb = x + (size_t)b * 3 * 448 * 448;
  u32* Arow = (u32*)(A + (size_t)t * KP);
  for (int h = threadIdx.x; h < KP / 2; h += 256) {
    int kk = h * 2;  // kk even: (kk,kk+1) share a patch row (14 and 588 are even)
    u32 v = 0;
    if (kk < CC) {
      int c = kk / 196, rem = kk - c * 196, i = rem / 14, j = rem - i * 14;
      const float* p = &xb[(size_t)(c * 448 + ph * 14 + i) * 448 + pw * 14 + j];
      v = pk2(p[0], p[1]);
    }
    Arow[h] = v;
  }
  if (t < 112) {
    u16* row = vT + ((size_t)(t * DV + HD)) * SEQ;
    for (int n = threadIdx.x; n < SEQ; n += 256) row[n] = 0x3F80;  // ones row
    for (int n = threadIdx.x; n < SEQ; n += 256) {
      u64* pq = (u64*)&qb[((size_t)t * SEQ + n) * DP + 40];
      u64* pk = (u64*)&kb[((size_t)t * SEQ + n) * DP + 40];
#pragma unroll
      for (int z = 0; z < 3; z++) { pq[z] = 0; pk[z] = 0; }  // all d-pads 40..63 -> 0
    }
  }
}

// ---------------- weight pad/convert ----------------
// r < 1792: Wq[r][c] = qkv_w (bf16, zero-padded)
// r >= 1792: WcT[i][c] = conv_w[c][i] transposed; row 588 = conv_b; rows 589.. = 0
__global__ void padw_k(const float* __restrict__ wq, const float* __restrict__ wc,
                       const float* __restrict__ cb, u16* __restrict__ dq, u16* __restrict__ dct) {
  int r = blockIdx.x;
  if (r < 1792) {
    for (int c = threadIdx.x; c < KP; c += 256) {
      float v = (r < C3 && c < CC) ? wq[(size_t)r * CC + c] : 0.f;
      dq[(size_t)r * KP + c] = f2b(v);
    }
  } else {
    int i = r - 1792;
    for (int c = threadIdx.x; c < KP; c += 256) {
      float v = 0.f;
      if (c < CC) {
        if (i < CC) v = wc[(size_t)c * CC + i];
        else if (i == CC) v = cb[c];
      }
      dct[(size_t)i * KP + c] = f2b(v);
    }
  }
}

// ---------------- 128x128x(BK=64) bf16 MFMA GEMM, C = A * Bt^T ----------------
// MODE 0 (wfuse): A=Wq[1792][640], Bt=WcT[640][640] -> Wfused[1792][640] bf16;
//                 col 588 => bfused[row] = qkv_b[row] + acc (fused bias)
// MODE 1 (qkv):   A=im2col[8192][640], Bt=Wfused -> Q (pre-scaled)/K scatter [b,h,n,64]; V -> vT b64
template <int MODE>
__global__ void __launch_bounds__(256, 2) gemm_k(
    const u16* __restrict__ A, const u16* __restrict__ Bt,
    const float* __restrict__ bias, u16* __restrict__ out0,
    u16* __restrict__ qb, u16* __restrict__ kb, u16* __restrict__ vb,
    float* __restrict__ bf) {
  __shared__ alignas(16) u16 sA[128 * 64];
  __shared__ alignas(16) u16 sB[128 * 64];
  const int tid = threadIdx.x;
  const int wave = tid >> 6, lane = tid & 63, quad = lane >> 4, l16 = lane & 15;
  const int wi = wave >> 1, wj = wave & 1;
  const int m0 = blockIdx.x * 128, n0 = blockIdx.y * 128;
  const int rL = lane >> 3, scid = lane & 7;
  const f32x4 z4 = {0.f, 0.f, 0.f, 0.f};

  f32x4 acc[4][4];
#pragma unroll
  for (int i = 0; i < 4; i++)
#pragma unroll
    for (int j = 0; j < 4; j++) acc[i][j] = z4;

  for (int k0 = 0; k0 < KP; k0 += 64) {
    __syncthreads();
#pragma unroll
    for (int cc = wave; cc < 16; cc += 4) {
      int r = cc * 8 + rL;
      gl_lds16(A + ((size_t)(m0 + r) * KP + k0 + (scid ^ (r & 7)) * 8), &sA[cc * 512]);
    }
#pragma unroll
    for (int cc = wave; cc < 16; cc += 4) {
      int r = cc * 8 + rL;
      gl_lds16(Bt + ((size_t)(n0 + r) * KP + k0 + (scid ^ (r & 7)) * 8), &sB[cc * 512]);
    }
    __syncthreads();
#pragma unroll
    for (int ks = 0; ks < 2; ks++) {
      bf16x8 af[4], bfr[4];
#pragma unroll
      for (int i = 0; i < 4; i++) {
        int r = wi * 64 + i * 16 + l16;
        af[i] = *(const bf16x8*)&sA[r * 64 + (((ks * 4 + quad) ^ (r & 7)) * 8)];
      }
#pragma unroll
      for (int j = 0; j < 4; j++) {
        int r = wj * 64 + j * 16 + l16;
        bfr[j] = *(const bf16x8*)&sB[r * 64 + (((ks * 4 + quad) ^ (r & 7)) * 8)];
      }
#pragma unroll
      for (int i = 0; i < 4; i++)
#pragma unroll
        for (int j = 0; j < 4; j++)
          acc[i][j] = __builtin_amdgcn_mfma_f32_16x16x32_bf16(af[i], bfr[j], acc[i][j], 0, 0, 0);
    }
  }

  const int baser = wi * 64 + quad * 4;  // C/D: col = lane&15, row = quad*4 + reg
  if (MODE == 0) {
#pragma unroll
    for (int j = 0; j < 4; j++) {
      int col = n0 + wj * 64 + j * 16 + l16;
#pragma unroll
      for (int i = 0; i < 4; i++) {
        int row = m0 + baser + i * 16;
#pragma unroll
        for (int r = 0; r < 4; r++) {
          out0[(size_t)(row + r) * KP + col] = f2b(acc[i][j][r]);
          if (col == CC && row + r < C3) bf[row + r] = bias[row + r] + acc[i][j][r];
        }
      }
    }
  } else {
#pragma unroll
    for (int j = 0; j < 4; j++) {
      int col = n0 + wj * 64 + j * 16 + l16;
      if (col < C3) {
        float bs = bias[col];
        int which = col / CC;
        int rem = col - which * CC;
        int h = rem / HD;
        int d = rem - h * HD;
        if (which < 2) {
          u16* dst = (which == 0) ? qb : kb;
          float sc = (which == 0) ? SC2f : 1.0f;  // pre-scale Q by 0.125*log2(e)
#pragma unroll
          for (int i = 0; i < 4; i++) {
            int row = m0 + baser + i * 16;
#pragma unroll
            for (int r = 0; r < 4; r++) {
              int rw = row + r;
              int b = rw >> 10, n = rw & 1023;
              dst[((size_t)((b * NH + h) * SEQ + n)) * DP + d] = f2b((acc[i][j][r] + bs) * sc);
            }
          }
        } else {  // V -> vT[bh][d][n], 4 consecutive n per lane -> b64 store
#pragma unroll
          for (int i = 0; i < 4; i++) {
            int row = m0 + baser + i * 16;
            int b = row >> 10, n = row & 1023;
            u64 pk = (u64)f2b(acc[i][j][0] + bs) | ((u64)f2b(acc[i][j][1] + bs) << 16) |
                     ((u64)f2b(acc[i][j][2] + bs) << 32) | ((u64)f2b(acc[i][j][3] + bs) << 48);
            *(u64*)&vb[((size_t)((b * NH + h) * DV + d)) * SEQ + n] = pk;
          }
        }
      }
    }
  }
}

// ---------------- attention: R6-exact 64-row Q tile, ping-pong K/V, 1 barrier/kt ----------------
// 4 waves x 16 q-rows; S tiles key-interleaved (tile j -> keys 4c+j) -> pk2 b64 P writes.
// sK staged with (r>>2)&7 XOR so interleaved-key B-frag reads are 2-way (free).
// Defensive s<=64 clamp before exp2: converts any garbage logit into finite error, never NaN.
__global__ void __launch_bounds__(256) attn_k(
    const u16* __restrict__ qb, const u16* __restrict__ kb,
    const u16* __restrict__ vT, float* __restrict__ out) {
  __shared__ alignas(16) u16 sK[2][64 * 64];    // 16 KB ping-pong
  __shared__ alignas(16) u16 sV[2][DV * 64];    // 12 KB ping-pong
  __shared__ alignas(16) u16 sP[4][16 * 72];    // 9 KB; per-wave private 16x64 P
  const int tid = threadIdx.x;
  const int wave = tid >> 6, lane = tid & 63, quad = lane >> 4, l16 = lane & 15;
  const int g = blockIdx.x;
  const int bh = (g & 7) * 14 + (g >> 7);   // XCD swizzle: one bh's 16 q-tiles share an XCD
  const int qt = (g >> 3) & 15;
  const int q0 = qt * 64;
  const int rL = lane >> 3, scid = lane & 7;
  const f32x4 z4 = {0.f, 0.f, 0.f, 0.f};
  u16* sPw = sP[wave];

  bf16x8 aq0, aq1;  // Q resident (pre-scaled); wave owns rows q0+wave*16..+15
  {
    const u16* qrow = qb + ((size_t)(bh * SEQ + q0 + wave * 16 + l16)) * DP;
    aq0 = *(const bf16x8*)&qrow[quad * 8];
    aq1 = *(const bf16x8*)&qrow[32 + quad * 8];
  }
  f32x4 o[3] = {z4, z4, z4};  // 16x48 accum; col 42 = row-sum (ones row of V^T)

  const u16* kb0 = kb + (size_t)bh * SEQ * DP;
  const u16* vb0 = vT + (size_t)bh * DV * SEQ;

#define STAGE(bufi, m0_)                                                                    \
  {                                                                                         \
    _Pragma("unroll") for (int cc = wave; cc < 8; cc += 4) {                                \
      int r = cc * 8 + rL;                                                                  \
      gl_lds16(kb0 + ((size_t)((m0_) + r)) * DP + (scid ^ ((r >> 2) & 7)) * 8,              \
               &sK[bufi][cc * 512]);                                                        \
    }                                                                                       \
    _Pragma("unroll") for (int cc = wave; cc < 6; cc += 4) {                                \
      int d = cc * 8 + rL;                                                                  \
      gl_lds16(vb0 + (size_t)d * SEQ + (m0_) + (scid ^ (d & 7)) * 8, &sV[bufi][cc * 512]);  \
    }                                                                                       \
  }

  STAGE(0, 0);  // prologue: tile 0 into buf 0

  for (int kt = 0; kt < 16; kt++) {
    __syncthreads();  // drains my DMA(kt); buf[(kt+1)&1] reads from kt-1 done block-wide
    if (kt < 15) STAGE((kt + 1) & 1, (kt + 1) * 64);  // prefetch overlaps whole compute(kt)
    const u16* sKb = sK[kt & 1];
    const u16* sVb = sV[kt & 1];
    // K B-frags, key-interleaved: tile j covers keys 4*l16+j
    bf16x8 bk[4][2];
#pragma unroll
    for (int j = 0; j < 4; j++) {
      int rr = 4 * l16 + j;
#pragma unroll
      for (int ks = 0; ks < 2; ks++)
        bk[j][ks] = *(const bf16x8*)&sKb[rr * 64 + (((ks * 4 + quad) ^ (l16 & 7)) * 8)];
    }
    // S = Q K^T, exp2 (clamped), pack 4 keys -> b64 (wave-private sP: no barrier)
    f32x4 s[4];
#pragma unroll
    for (int j = 0; j < 4; j++) {
      f32x4 t = __builtin_amdgcn_mfma_f32_16x16x32_bf16(aq0, bk[j][0], z4, 0, 0, 0);
      s[j] = __builtin_amdgcn_mfma_f32_16x16x32_bf16(aq1, bk[j][1], t, 0, 0, 0);
    }
#pragma unroll
    for (int r = 0; r < 4; r++) {
      float e0 = __builtin_amdgcn_exp2f(fminf(s[0][r], 64.f));
      float e1 = __builtin_amdgcn_exp2f(fminf(s[1][r], 64.f));
      float e2 = __builtin_amdgcn_exp2f(fminf(s[2][r], 64.f));
      float e3 = __builtin_amdgcn_exp2f(fminf(s[3][r], 64.f));
      u32* dst = (u32*)&sPw[(quad * 4 + r) * 72 + l16 * 4];
      dst[0] = pk2(e0, e1);
      dst[1] = pk2(e2, e3);
    }
    // O += P V
#pragma unroll
    for (int ks = 0; ks < 2; ks++) {
      bf16x8 ap = *(const bf16x8*)&sPw[l16 * 72 + ks * 32 + quad * 8];
#pragma unroll
      for (int j = 0; j < 3; j++) {
        int d = j * 16 + l16;
        bf16x8 bv = *(const bf16x8*)&sVb[d * 64 + (((ks * 4 + quad) ^ (d & 7)) * 8)];
        o[j] = __builtin_amdgcn_mfma_f32_16x16x32_bf16(ap, bv, o[j], 0, 0, 0);
      }
    }
  }
#undef STAGE

  // epilogue: row-sum = col 42 of o[2] (lane quad*16+10); intra-wave shuffle broadcast
  const int b = bh / NH, h = bh - b * NH;
#pragma unroll
  for (int r = 0; r < 4; r++) {
    float ls = __shfl(o[2][r], (lane & 48) + 10, 64);
    float rc = 1.f / ls;
    int row = wave * 16 + quad * 4 + r;
    float* orow = out + ((size_t)(b * SEQ + q0 + row)) * CC + h * HD;
#pragma unroll
    for (int j = 0; j < 3; j++) {
      int d = j * 16 + l16;
      if (d < HD) orow[d] = o[j][r] * rc;
    }
  }
}

extern "C" void kernel_launch(void* const* d_in, const int* in_sizes, int n_in,
                              void* d_out, int out_size, void* d_ws, size_t ws_size,
                              hipStream_t stream) {
  (void)in_sizes; (void)n_in; (void)out_size; (void)ws_size;
  const float* x      = (const float*)d_in[0];
  const float* conv_w = (const float*)d_in[1];
  const float* conv_b = (const float*)d_in[2];
  const float* qkv_w  = (const float*)d_in[3];
  const float* qkv_b  = (const float*)d_in[4];
  float* out = (float*)d_out;

  char* ws = (char*)d_ws;
  size_t off = 0;
  u16* A      = (u16*)(ws + off); off += (size_t)MTOK * KP * 2;       // 10.5 MB
  u16* Wq     = (u16*)(ws + off); off += (size_t)1792 * KP * 2;       // 2.3 MB
  u16* WcT    = (u16*)(ws + off); off += (size_t)640 * KP * 2;        // 0.8 MB
  u16* Wf     = (u16*)(ws + off); off += (size_t)1792 * KP * 2;       // 2.3 MB
  float* bfus = (float*)(ws + off); off += (size_t)C3 * 4;            // 7 KB
  off = (off + 255) & ~(size_t)255;
  u16* qbuf   = (u16*)(ws + off); off += (size_t)112 * SEQ * DP * 2;  // 14.7 MB
  u16* kbuf   = (u16*)(ws + off); off += (size_t)112 * SEQ * DP * 2;  // 14.7 MB
  u16* vTb    = (u16*)(ws + off); off += (size_t)112 * DV * SEQ * 2;  // 11.0 MB

  im2col_k<<<MTOK, 256, 0, stream>>>(x, A, vTb, qbuf, kbuf);
  padw_k<<<2432, 256, 0, stream>>>(qkv_w, conv_w, conv_b, Wq, WcT);
  // Wfused = Wq * Wc (+ fused bias in col 588): front-end collapses into one token GEMM
  gemm_k<0><<<dim3(14, 5), 256, 0, stream>>>(Wq, WcT, qkv_b, Wf, nullptr, nullptr, nullptr, bfus);
  gemm_k<1><<<dim3(64, 14), 256, 0, stream>>>(A, Wf, bfus, nullptr, qbuf, kbuf, vTb, nullptr);
  attn_k<<<1792, 256, 0, stream>>>(qbuf, kbuf, vTb, out);
}

// Round 10
// 182.564 us; speedup vs baseline: 1.0316x; 1.0316x over previous
//
#include <hip/hip_runtime.h>

typedef unsigned short u16;
typedef unsigned int u32;
typedef unsigned long long u64;
typedef __attribute__((ext_vector_type(8))) short bf16x8;   // 8 bf16 (4 VGPRs)
typedef __attribute__((ext_vector_type(4))) float f32x4;    // MFMA C/D frag

#define MTOK 8192   // B*N tokens
#define KP   640    // K padded (588 -> 640 = 10*64)
#define CC   588
#define C3   1764
#define NH   14
#define SEQ  1024
#define HD   42
#define DP   64     // head-dim padded for QK^T K-loop
#define DV   48     // V^T rows: 42 real + ones row (42) + junk(43..47, unused cols)
#define SC2f 0.18033688011112042f  // 0.125 * log2(e)

static __device__ __forceinline__ u16 f2b(float f) {  // fp32 -> bf16 RNE
  unsigned u = __builtin_bit_cast(unsigned, f);
  u = (u + 0x7FFFu + ((u >> 16) & 1u)) >> 16;
  return (u16)u;
}

static __device__ __forceinline__ void gl_lds16(const void* g, void* l) {
  auto gp = (const unsigned int __attribute__((address_space(1)))*)((unsigned long long)g);
  auto lp = (unsigned int __attribute__((address_space(3)))*)((unsigned long long)l);
  __builtin_amdgcn_global_load_lds(gp, lp, 16, 0, 0);
}

// pack two fp32 -> (bf16(hi)<<16)|bf16(lo), round-half-up (1-ulp-equiv to RNE; softmax-norm safe)
static __device__ __forceinline__ u32 pk2(float lo, float hi) {
  u32 a = __builtin_bit_cast(u32, lo) + 0x8000u;
  u32 b = __builtin_bit_cast(u32, hi) + 0x8000u;
  return __builtin_amdgcn_perm(b, a, 0x07060302u);  // {hi16(b), hi16(a)}
}

// ---------------- im2col: x [8,3,448,448] f32 -> A [8192][640] bf16 (u32-paired stores) ----------------
// blocks 0..111 additionally: vT ones-row (d=42) + q/k d-pad zeros (d 40..63; gemm1 rewrites 40,41)
__global__ void im2col_k(const float* __restrict__ x, u16* __restrict__ A,
                         u16* __restrict__ vT, u16* __restrict__ qb, u16* __restrict__ kb) {
  int t = blockIdx.x;
  int b = t >> 10, pi = t & 1023, ph = pi >> 5, pw = pi & 31;
  const float* xb = x + (size_t)b * 3 * 448 * 448;
  u32* Arow = (u32*)(A + (size_t)t * KP);
  for (int h = threadIdx.x; h < KP / 2; h += 256) {
    int kk = h * 2;  // kk even: (kk,kk+1) share a patch row (14 and 588 are even)
    u32 v = 0;
    if (kk < CC) {
      int c = kk / 196, rem = kk - c * 196, i = rem / 14, j = rem - i * 14;
      const float* p = &xb[(size_t)(c * 448 + ph * 14 + i) * 448 + pw * 14 + j];
      v = pk2(p[0], p[1]);
    }
    Arow[h] = v;
  }
  if (t < 112) {
    u16* row = vT + ((size_t)(t * DV + HD)) * SEQ;
    for (int n = threadIdx.x; n < SEQ; n += 256) row[n] = 0x3F80;  // ones row
    for (int n = threadIdx.x; n < SEQ; n += 256) {
      u64* pq = (u64*)&qb[((size_t)t * SEQ + n) * DP + 40];
      u64* pk = (u64*)&kb[((size_t)t * SEQ + n) * DP + 40];
#pragma unroll
      for (int z = 0; z < 3; z++) { pq[z] = 0; pk[z] = 0; }  // all d-pads 40..63 -> 0
    }
  }
}

// ---------------- merged weight pad/convert: conv rows 0..639, qkv rows 640..2431 ----------------
__global__ void padw_k(const float* __restrict__ wc, const float* __restrict__ wq,
                       u16* __restrict__ dc, u16* __restrict__ dq) {
  int r = blockIdx.x;
  const float* src; u16* dst; int R, rr;
  if (r < 640) { src = wc; dst = dc; R = CC; rr = r; }
  else         { src = wq; dst = dq; R = C3; rr = r - 640; }
  for (int c = threadIdx.x; c < KP; c += 256) {
    float v = (rr < R && c < CC) ? src[(size_t)rr * CC + c] : 0.f;
    dst[(size_t)rr * KP + c] = f2b(v);
  }
}

// ---------------- 128x128x(BK=64) bf16 MFMA GEMM, C = A * Bt^T ----------------
// MODE 0: tokens epilogue (+conv bias, bf16 out, stride KP)
// MODE 1: qkv epilogue: Q (pre-scaled) / K -> [b,h,n,64] scatter; V -> vT [bh][d][n] b64 stores
template <int MODE>
__global__ void __launch_bounds__(256, 2) gemm_k(
    const u16* __restrict__ A, const u16* __restrict__ Bt,
    const float* __restrict__ bias, u16* __restrict__ out0,
    u16* __restrict__ qb, u16* __restrict__ kb, u16* __restrict__ vb) {
  __shared__ alignas(16) u16 sA[128 * 64];
  __shared__ alignas(16) u16 sB[128 * 64];
  const int tid = threadIdx.x;
  const int wave = tid >> 6, lane = tid & 63, quad = lane >> 4, l16 = lane & 15;
  const int wi = wave >> 1, wj = wave & 1;
  const int m0 = blockIdx.x * 128, n0 = blockIdx.y * 128;
  const int rL = lane >> 3, scid = lane & 7;
  const f32x4 z4 = {0.f, 0.f, 0.f, 0.f};

  f32x4 acc[4][4];
#pragma unroll
  for (int i = 0; i < 4; i++)
#pragma unroll
    for (int j = 0; j < 4; j++) acc[i][j] = z4;

  for (int k0 = 0; k0 < KP; k0 += 64) {
    __syncthreads();
#pragma unroll
    for (int cc = wave; cc < 16; cc += 4) {
      int r = cc * 8 + rL;
      gl_lds16(A + ((size_t)(m0 + r) * KP + k0 + (scid ^ (r & 7)) * 8), &sA[cc * 512]);
    }
#pragma unroll
    for (int cc = wave; cc < 16; cc += 4) {
      int r = cc * 8 + rL;
      gl_lds16(Bt + ((size_t)(n0 + r) * KP + k0 + (scid ^ (r & 7)) * 8), &sB[cc * 512]);
    }
    __syncthreads();
#pragma unroll
    for (int ks = 0; ks < 2; ks++) {
      bf16x8 af[4], bfr[4];
#pragma unroll
      for (int i = 0; i < 4; i++) {
        int r = wi * 64 + i * 16 + l16;
        af[i] = *(const bf16x8*)&sA[r * 64 + (((ks * 4 + quad) ^ (r & 7)) * 8)];
      }
#pragma unroll
      for (int j = 0; j < 4; j++) {
        int r = wj * 64 + j * 16 + l16;
        bfr[j] = *(const bf16x8*)&sB[r * 64 + (((ks * 4 + quad) ^ (r & 7)) * 8)];
      }
#pragma unroll
      for (int i = 0; i < 4; i++)
#pragma unroll
        for (int j = 0; j < 4; j++)
          acc[i][j] = __builtin_amdgcn_mfma_f32_16x16x32_bf16(af[i], bfr[j], acc[i][j], 0, 0, 0);
    }
  }

  const int baser = wi * 64 + quad * 4;  // C/D: col = lane&15, row = quad*4 + reg
  if (MODE == 0) {
#pragma unroll
    for (int j = 0; j < 4; j++) {
      int col = n0 + wj * 64 + j * 16 + l16;
      float bs = (col < CC) ? bias[col] : 0.f;
#pragma unroll
      for (int i = 0; i < 4; i++) {
        int row = m0 + baser + i * 16;
#pragma unroll
        for (int r = 0; r < 4; r++)
          out0[(size_t)(row + r) * KP + col] = f2b(acc[i][j][r] + bs);
      }
    }
  } else {
#pragma unroll
    for (int j = 0; j < 4; j++) {
      int col = n0 + wj * 64 + j * 16 + l16;
      if (col < C3) {
        float bs = bias[col];
        int which = col / CC;
        int rem = col - which * CC;
        int h = rem / HD;
        int d = rem - h * HD;
        if (which < 2) {
          u16* dst = (which == 0) ? qb : kb;
          float sc = (which == 0) ? SC2f : 1.0f;  // pre-scale Q by 0.125*log2(e)
#pragma unroll
          for (int i = 0; i < 4; i++) {
            int row = m0 + baser + i * 16;
#pragma unroll
            for (int r = 0; r < 4; r++) {
              int rw = row + r;
              int b = rw >> 10, n = rw & 1023;
              dst[((size_t)((b * NH + h) * SEQ + n)) * DP + d] = f2b((acc[i][j][r] + bs) * sc);
            }
          }
        } else {  // V -> vT[bh][d][n], 4 consecutive n per lane -> b64 store
#pragma unroll
          for (int i = 0; i < 4; i++) {
            int row = m0 + baser + i * 16;
            int b = row >> 10, n = row & 1023;
            u64 pk = (u64)f2b(acc[i][j][0] + bs) | ((u64)f2b(acc[i][j][1] + bs) << 16) |
                     ((u64)f2b(acc[i][j][2] + bs) << 32) | ((u64)f2b(acc[i][j][3] + bs) << 48);
            *(u64*)&vb[((size_t)((b * NH + h) * DV + d)) * SEQ + n] = pk;
          }
        }
      }
    }
  }
}

// ---------------- attention: R4-exact 128-row Q tile, single-buffer LDS staging ----------------
// 4 waves x 32 q-rows. S tiles key-interleaved (tile j -> keys 4c+j) -> pk2 b64 P writes.
// sK staged with (r>>2)&7 XOR so interleaved-key B-frag reads are 2-way (free).
__global__ void __launch_bounds__(256) attn_k(
    const u16* __restrict__ qb, const u16* __restrict__ kb,
    const u16* __restrict__ vT, float* __restrict__ out) {
  __shared__ alignas(16) u16 sK[64 * 64];    // 8 KB
  __shared__ alignas(16) u16 sV[DV * 64];    // 6 KB
  __shared__ alignas(16) u16 sP[4][32 * 72]; // 18 KB; per-wave private 32x64 P (row stride 72)
  const int tid = threadIdx.x;
  const int wave = tid >> 6, lane = tid & 63, quad = lane >> 4, l16 = lane & 15;
  const int g = blockIdx.x;
  const int bh = (g & 7) * 14 + (g >> 6);   // XCD swizzle: one bh's 8 q-tiles share an XCD
  const int qt = (g >> 3) & 7;
  const int q0 = qt * 128;
  const int rL = lane >> 3, scid = lane & 7;
  const f32x4 z4 = {0.f, 0.f, 0.f, 0.f};
  u16* sPw = sP[wave];

  bf16x8 aq[2][2];  // Q resident (pre-scaled); wave owns rows q0+wave*32..+31
#pragma unroll
  for (int i = 0; i < 2; i++) {
    const u16* qrow = qb + ((size_t)(bh * SEQ + q0 + wave * 32 + i * 16 + l16)) * DP;
    aq[i][0] = *(const bf16x8*)&qrow[quad * 8];
    aq[i][1] = *(const bf16x8*)&qrow[32 + quad * 8];
  }
  f32x4 o[2][3];  // 32x48 accum; col 42 = row-sum (ones row of V^T)
#pragma unroll
  for (int i = 0; i < 2; i++)
#pragma unroll
    for (int j = 0; j < 3; j++) o[i][j] = z4;

  const u16* kb0 = kb + (size_t)bh * SEQ * DP;
  const u16* vb0 = vT + (size_t)bh * DV * SEQ;

  for (int kt = 0; kt < 16; kt++) {
    const int m0 = kt * 64;
    __syncthreads();  // prior iter's sK/sV reads done
#pragma unroll
    for (int cc = wave; cc < 8; cc += 4) {
      int r = cc * 8 + rL;
      gl_lds16(kb0 + ((size_t)(m0 + r)) * DP + (scid ^ ((r >> 2) & 7)) * 8, &sK[cc * 512]);
    }
#pragma unroll
    for (int cc = wave; cc < 6; cc += 4) {
      int d = cc * 8 + rL;
      gl_lds16(vb0 + (size_t)d * SEQ + m0 + (scid ^ (d & 7)) * 8, &sV[cc * 512]);
    }
    __syncthreads();
    // K B-frags, key-interleaved: tile j covers keys 4*l16+j (shared across both i-blocks)
    bf16x8 bk[4][2];
#pragma unroll
    for (int j = 0; j < 4; j++) {
      int rr = 4 * l16 + j;
#pragma unroll
      for (int ks = 0; ks < 2; ks++)
        bk[j][ks] = *(const bf16x8*)&sK[rr * 64 + (((ks * 4 + quad) ^ (l16 & 7)) * 8)];
    }
    // S = Q K^T, exp2, pack 4 keys -> b64 (wave-private sP: no barrier)
#pragma unroll
    for (int i = 0; i < 2; i++) {
      f32x4 s[4];
#pragma unroll
      for (int j = 0; j < 4; j++) {
        f32x4 t = __builtin_amdgcn_mfma_f32_16x16x32_bf16(aq[i][0], bk[j][0], z4, 0, 0, 0);
        s[j] = __builtin_amdgcn_mfma_f32_16x16x32_bf16(aq[i][1], bk[j][1], t, 0, 0, 0);
      }
#pragma unroll
      for (int r = 0; r < 4; r++) {
        u32 d0 = pk2(__builtin_amdgcn_exp2f(s[0][r]), __builtin_amdgcn_exp2f(s[1][r]));
        u32 d1 = pk2(__builtin_amdgcn_exp2f(s[2][r]), __builtin_amdgcn_exp2f(s[3][r]));
        u32* dst = (u32*)&sPw[(i * 16 + quad * 4 + r) * 72 + l16 * 4];
        dst[0] = d0;
        dst[1] = d1;
      }
    }
    // O += P V
#pragma unroll
    for (int ks = 0; ks < 2; ks++) {
      bf16x8 bv[3];
#pragma unroll
      for (int j = 0; j < 3; j++) {
        int d = j * 16 + l16;
        bv[j] = *(const bf16x8*)&sV[d * 64 + (((ks * 4 + quad) ^ (d & 7)) * 8)];
      }
#pragma unroll
      for (int i = 0; i < 2; i++) {
        bf16x8 ap = *(const bf16x8*)&sPw[(i * 16 + l16) * 72 + ks * 32 + quad * 8];
#pragma unroll
        for (int j = 0; j < 3; j++)
          o[i][j] = __builtin_amdgcn_mfma_f32_16x16x32_bf16(ap, bv[j], o[i][j], 0, 0, 0);
      }
    }
  }

  // epilogue: row-sum = col 42 of o[i][2] (lane quad*16+10); intra-wave shuffle broadcast
  const int b = bh / NH, h = bh - b * NH;
#pragma unroll
  for (int i = 0; i < 2; i++) {
#pragma unroll
    for (int r = 0; r < 4; r++) {
      float ls = __shfl(o[i][2][r], (lane & 48) + 10, 64);
      float rc = 1.f / ls;
      int row = wave * 32 + i * 16 + quad * 4 + r;
      float* orow = out + ((size_t)(b * SEQ + q0 + row)) * CC + h * HD;
#pragma unroll
      for (int j = 0; j < 3; j++) {
        int d = j * 16 + l16;
        if (d < HD) orow[d] = o[i][j][r] * rc;
      }
    }
  }
}

extern "C" void kernel_launch(void* const* d_in, const int* in_sizes, int n_in,
                              void* d_out, int out_size, void* d_ws, size_t ws_size,
                              hipStream_t stream) {
  (void)in_sizes; (void)n_in; (void)out_size; (void)ws_size;
  const float* x      = (const float*)d_in[0];
  const float* conv_w = (const float*)d_in[1];
  const float* conv_b = (const float*)d_in[2];
  const float* qkv_w  = (const float*)d_in[3];
  const float* qkv_b  = (const float*)d_in[4];
  float* out = (float*)d_out;

  char* ws = (char*)d_ws;
  size_t off = 0;
  u16* A      = (u16*)(ws + off); off += (size_t)MTOK * KP * 2;       // 10.5 MB
  u16* Wc     = (u16*)(ws + off); off += (size_t)640 * KP * 2;        // 0.8 MB
  u16* Wq     = (u16*)(ws + off); off += (size_t)1792 * KP * 2;       // 2.3 MB
  u16* tokens = (u16*)(ws + off); off += (size_t)MTOK * KP * 2;       // 10.5 MB
  u16* qbuf   = (u16*)(ws + off); off += (size_t)112 * SEQ * DP * 2;  // 14.7 MB
  u16* kbuf   = (u16*)(ws + off); off += (size_t)112 * SEQ * DP * 2;  // 14.7 MB
  u16* vTb    = (u16*)(ws + off); off += (size_t)112 * DV * SEQ * 2;  // 11.0 MB

  im2col_k<<<MTOK, 256, 0, stream>>>(x, A, vTb, qbuf, kbuf);
  padw_k<<<2432, 256, 0, stream>>>(conv_w, qkv_w, Wc, Wq);
  gemm_k<0><<<dim3(64, 5), 256, 0, stream>>>(A, Wc, conv_b, tokens, nullptr, nullptr, nullptr);
  gemm_k<1><<<dim3(64, 14), 256, 0, stream>>>(tokens, Wq, qkv_b, nullptr, qbuf, kbuf, vTb);
  attn_k<<<896, 256, 0, stream>>>(qbuf, kbuf, vTb, out);
}

// Round 11
// 173.731 us; speedup vs baseline: 1.0840x; 1.0508x over previous
//
#include <hip/hip_runtime.h>

typedef unsigned short u16;
typedef unsigned int u32;
typedef unsigned long long u64;
typedef __attribute__((ext_vector_type(8))) short bf16x8;   // 8 bf16 (4 VGPRs)
typedef __attribute__((ext_vector_type(4))) float f32x4;    // MFMA C/D frag

#define MTOK 8192   // B*N tokens
#define KP   640    // K padded (588 -> 640 = 10*64)
#define CC   588
#define C3   1764
#define NH   14
#define SEQ  1024
#define HD   42
#define DP   64     // head-dim padded for QK^T K-loop
#define DV   48     // V^T rows: 42 real + ones row (42) + junk(43..47, unused cols)
#define SC2f 0.18033688011112042f  // 0.125 * log2(e)

static __device__ __forceinline__ u16 f2b(float f) {  // fp32 -> bf16 RNE
  unsigned u = __builtin_bit_cast(unsigned, f);
  u = (u + 0x7FFFu + ((u >> 16) & 1u)) >> 16;
  return (u16)u;
}

static __device__ __forceinline__ void gl_lds16(const void* g, void* l) {
  auto gp = (const unsigned int __attribute__((address_space(1)))*)((unsigned long long)g);
  auto lp = (unsigned int __attribute__((address_space(3)))*)((unsigned long long)l);
  __builtin_amdgcn_global_load_lds(gp, lp, 16, 0, 0);
}

// pack two fp32 -> (bf16(hi)<<16)|bf16(lo), round-half-up (1-ulp-equiv to RNE; softmax-norm safe)
static __device__ __forceinline__ u32 pk2(float lo, float hi) {
  u32 a = __builtin_bit_cast(u32, lo) + 0x8000u;
  u32 b = __builtin_bit_cast(u32, hi) + 0x8000u;
  return __builtin_amdgcn_perm(b, a, 0x07060302u);  // {hi16(b), hi16(a)}
}

// ---------------- prep: merged im2col + weight pad/convert ----------------
// blocks 0..8191: im2col token t; blocks 0..111 also vT ones-row + q/k d-pad zeros
// blocks 8192..10623: weight rows (conv 0..639, qkv 640..2431)
__global__ void prep_k(const float* __restrict__ x, u16* __restrict__ A,
                       u16* __restrict__ vT, u16* __restrict__ qb, u16* __restrict__ kb,
                       const float* __restrict__ wc, const float* __restrict__ wq,
                       u16* __restrict__ Wc, u16* __restrict__ Wq) {
  int t = blockIdx.x;
  if (t < MTOK) {
    int b = t >> 10, pi = t & 1023, ph = pi >> 5, pw = pi & 31;
    const float* xb = x + (size_t)b * 3 * 448 * 448;
    u32* Arow = (u32*)(A + (size_t)t * KP);
    for (int h = threadIdx.x; h < KP / 2; h += 256) {
      int kk = h * 2;  // kk even: (kk,kk+1) share a patch row (14 and 588 are even)
      u32 v = 0;
      if (kk < CC) {
        int c = kk / 196, rem = kk - c * 196, i = rem / 14, j = rem - i * 14;
        const float* p = &xb[(size_t)(c * 448 + ph * 14 + i) * 448 + pw * 14 + j];
        v = pk2(p[0], p[1]);
      }
      Arow[h] = v;
    }
    if (t < 112) {
      u16* row = vT + ((size_t)(t * DV + HD)) * SEQ;
      for (int n = threadIdx.x; n < SEQ; n += 256) row[n] = 0x3F80;  // ones row
      for (int n = threadIdx.x; n < SEQ; n += 256) {
        u64* pq = (u64*)&qb[((size_t)t * SEQ + n) * DP + 40];
        u64* pk = (u64*)&kb[((size_t)t * SEQ + n) * DP + 40];
#pragma unroll
        for (int z = 0; z < 3; z++) { pq[z] = 0; pk[z] = 0; }  // all d-pads 40..63 -> 0
      }
    }
  } else {
    int r = t - MTOK;
    const float* src; u16* dst; int R, rr;
    if (r < 640) { src = wc; dst = Wc; R = CC; rr = r; }
    else         { src = wq; dst = Wq; R = C3; rr = r - 640; }
    for (int c = threadIdx.x; c < KP; c += 256) {
      float v = (rr < R && c < CC) ? src[(size_t)rr * CC + c] : 0.f;
      dst[(size_t)rr * KP + c] = f2b(v);
    }
  }
}

// ---------------- 128x128x(BK=64) bf16 MFMA GEMM, C = A * Bt^T ----------------
// MODE 0: tokens epilogue (+conv bias, bf16 out, stride KP) — already coalesced
// MODE 1: qkv epilogue: V -> vT b64 from regs; Q (pre-scaled) / K via LDS transpose ->
//         coalesced u32 stores along d (pairs never straddle head bounds: 588, 42 even)
template <int MODE>
__global__ void __launch_bounds__(256, 2) gemm_k(
    const u16* __restrict__ A, const u16* __restrict__ Bt,
    const float* __restrict__ bias, u16* __restrict__ out0,
    u16* __restrict__ qb, u16* __restrict__ kb, u16* __restrict__ vb) {
  __shared__ alignas(16) u16 smem[128 * 136];  // 34.8 KB; k-loop uses first 32 KB as sA|sB
  u16* sA = smem;
  u16* sB = smem + 128 * 64;
  const int tid = threadIdx.x;
  const int wave = tid >> 6, lane = tid & 63, quad = lane >> 4, l16 = lane & 15;
  const int wi = wave >> 1, wj = wave & 1;
  const int m0 = blockIdx.x * 128, n0 = blockIdx.y * 128;
  const int rL = lane >> 3, scid = lane & 7;
  const f32x4 z4 = {0.f, 0.f, 0.f, 0.f};

  f32x4 acc[4][4];
#pragma unroll
  for (int i = 0; i < 4; i++)
#pragma unroll
    for (int j = 0; j < 4; j++) acc[i][j] = z4;

  for (int k0 = 0; k0 < KP; k0 += 64) {
    __syncthreads();
#pragma unroll
    for (int cc = wave; cc < 16; cc += 4) {
      int r = cc * 8 + rL;
      gl_lds16(A + ((size_t)(m0 + r) * KP + k0 + (scid ^ (r & 7)) * 8), &sA[cc * 512]);
    }
#pragma unroll
    for (int cc = wave; cc < 16; cc += 4) {
      int r = cc * 8 + rL;
      gl_lds16(Bt + ((size_t)(n0 + r) * KP + k0 + (scid ^ (r & 7)) * 8), &sB[cc * 512]);
    }
    __syncthreads();
#pragma unroll
    for (int ks = 0; ks < 2; ks++) {
      bf16x8 af[4], bfr[4];
#pragma unroll
      for (int i = 0; i < 4; i++) {
        int r = wi * 64 + i * 16 + l16;
        af[i] = *(const bf16x8*)&sA[r * 64 + (((ks * 4 + quad) ^ (r & 7)) * 8)];
      }
#pragma unroll
      for (int j = 0; j < 4; j++) {
        int r = wj * 64 + j * 16 + l16;
        bfr[j] = *(const bf16x8*)&sB[r * 64 + (((ks * 4 + quad) ^ (r & 7)) * 8)];
      }
#pragma unroll
      for (int i = 0; i < 4; i++)
#pragma unroll
        for (int j = 0; j < 4; j++)
          acc[i][j] = __builtin_amdgcn_mfma_f32_16x16x32_bf16(af[i], bfr[j], acc[i][j], 0, 0, 0);
    }
  }

  const int baser = wi * 64 + quad * 4;  // C/D: col = lane&15, row = quad*4 + reg
  if (MODE == 0) {
#pragma unroll
    for (int j = 0; j < 4; j++) {
      int col = n0 + wj * 64 + j * 16 + l16;
      float bs = (col < CC) ? bias[col] : 0.f;
#pragma unroll
      for (int i = 0; i < 4; i++) {
        int row = m0 + baser + i * 16;
#pragma unroll
        for (int r = 0; r < 4; r++)
          out0[(size_t)(row + r) * KP + col] = f2b(acc[i][j][r] + bs);
      }
    }
  } else {
    __syncthreads();  // k-loop LDS reads done before tile overwrite
#pragma unroll
    for (int j = 0; j < 4; j++) {
      int col = n0 + wj * 64 + j * 16 + l16;
      if (col < C3) {
        float bs = bias[col];
        int which = col / CC;
        if (which == 2) {  // V -> vT[bh][d][n], 4 consecutive n per lane -> b64 store
          int rem = col - 2 * CC;
          int h = rem / HD, d = rem - h * HD;
#pragma unroll
          for (int i = 0; i < 4; i++) {
            int row = m0 + baser + i * 16;
            int b = row >> 10, n = row & 1023;
            u64 pk = (u64)f2b(acc[i][j][0] + bs) | ((u64)f2b(acc[i][j][1] + bs) << 16) |
                     ((u64)f2b(acc[i][j][2] + bs) << 32) | ((u64)f2b(acc[i][j][3] + bs) << 48);
            *(u64*)&vb[((size_t)((b * NH + h) * DV + d)) * SEQ + n] = pk;
          }
        } else {  // Q/K -> LDS tile (transpose round-trip)
          float sc = (which == 0) ? SC2f : 1.0f;  // pre-scale Q by 0.125*log2(e)
          int lcol = wj * 64 + j * 16 + l16;
#pragma unroll
          for (int i = 0; i < 4; i++) {
            int lrow = baser + i * 16;
#pragma unroll
            for (int r = 0; r < 4; r++)
              smem[(lrow + r) * 136 + lcol] = f2b((acc[i][j][r] + bs) * sc);
          }
        }
      }
    }
    __syncthreads();
    // coalesced pass: thread -> channel pair (c2, c2+1); iterate 32 token-rows; u32 stores
    {
      const int c2 = 2 * (tid & 63);
      const int w = tid >> 6;
      int gcol = n0 + c2;
      if (gcol < C3) {
        int which = gcol / CC;
        if (which < 2) {
          int rem = gcol - which * CC;
          int h = rem / HD, d = rem - h * HD;  // d even; pair stays in-head (42 even)
          u16* dstp = (which == 0) ? qb : kb;
          const int b = m0 >> 10, nb = m0 & 1023;
          u32* base = (u32*)&dstp[((size_t)((b * NH + h) * SEQ + nb)) * DP + d];
#pragma unroll
          for (int rr = 0; rr < 32; rr++) {
            int row = w * 32 + rr;
            base[(size_t)row * (DP / 2)] = *(const u32*)&smem[row * 136 + c2];
          }
        }
      }
    }
  }
}

// ---------------- attention: R10-exact 128-row Q tile, single-buffer LDS staging ----------------
// 4 waves x 32 q-rows. S tiles key-interleaved (tile j -> keys 4c+j) -> pk2 b64 P writes.
// sK staged with (r>>2)&7 XOR so interleaved-key B-frag reads are 2-way (free).
__global__ void __launch_bounds__(256) attn_k(
    const u16* __restrict__ qb, const u16* __restrict__ kb,
    const u16* __restrict__ vT, float* __restrict__ out) {
  __shared__ alignas(16) u16 sK[64 * 64];    // 8 KB
  __shared__ alignas(16) u16 sV[DV * 64];    // 6 KB
  __shared__ alignas(16) u16 sP[4][32 * 72]; // 18 KB; per-wave private 32x64 P (row stride 72)
  const int tid = threadIdx.x;
  const int wave = tid >> 6, lane = tid & 63, quad = lane >> 4, l16 = lane & 15;
  const int g = blockIdx.x;
  const int bh = (g & 7) * 14 + (g >> 6);   // XCD swizzle: one bh's 8 q-tiles share an XCD
  const int qt = (g >> 3) & 7;
  const int q0 = qt * 128;
  const int rL = lane >> 3, scid = lane & 7;
  const f32x4 z4 = {0.f, 0.f, 0.f, 0.f};
  u16* sPw = sP[wave];

  bf16x8 aq[2][2];  // Q resident (pre-scaled); wave owns rows q0+wave*32..+31
#pragma unroll
  for (int i = 0; i < 2; i++) {
    const u16* qrow = qb + ((size_t)(bh * SEQ + q0 + wave * 32 + i * 16 + l16)) * DP;
    aq[i][0] = *(const bf16x8*)&qrow[quad * 8];
    aq[i][1] = *(const bf16x8*)&qrow[32 + quad * 8];
  }
  f32x4 o[2][3];  // 32x48 accum; col 42 = row-sum (ones row of V^T)
#pragma unroll
  for (int i = 0; i < 2; i++)
#pragma unroll
    for (int j = 0; j < 3; j++) o[i][j] = z4;

  const u16* kb0 = kb + (size_t)bh * SEQ * DP;
  const u16* vb0 = vT + (size_t)bh * DV * SEQ;

  for (int kt = 0; kt < 16; kt++) {
    const int m0 = kt * 64;
    __syncthreads();  // prior iter's sK/sV reads done
#pragma unroll
    for (int cc = wave; cc < 8; cc += 4) {
      int r = cc * 8 + rL;
      gl_lds16(kb0 + ((size_t)(m0 + r)) * DP + (scid ^ ((r >> 2) & 7)) * 8, &sK[cc * 512]);
    }
#pragma unroll
    for (int cc = wave; cc < 6; cc += 4) {
      int d = cc * 8 + rL;
      gl_lds16(vb0 + (size_t)d * SEQ + m0 + (scid ^ (d & 7)) * 8, &sV[cc * 512]);
    }
    __syncthreads();
    // K B-frags, key-interleaved: tile j covers keys 4*l16+j (shared across both i-blocks)
    bf16x8 bk[4][2];
#pragma unroll
    for (int j = 0; j < 4; j++) {
      int rr = 4 * l16 + j;
#pragma unroll
      for (int ks = 0; ks < 2; ks++)
        bk[j][ks] = *(const bf16x8*)&sK[rr * 64 + (((ks * 4 + quad) ^ (l16 & 7)) * 8)];
    }
    // S = Q K^T, exp2, pack 4 keys -> b64 (wave-private sP: no barrier)
#pragma unroll
    for (int i = 0; i < 2; i++) {
      f32x4 s[4];
#pragma unroll
      for (int j = 0; j < 4; j++) {
        f32x4 t = __builtin_amdgcn_mfma_f32_16x16x32_bf16(aq[i][0], bk[j][0], z4, 0, 0, 0);
        s[j] = __builtin_amdgcn_mfma_f32_16x16x32_bf16(aq[i][1], bk[j][1], t, 0, 0, 0);
      }
#pragma unroll
      for (int r = 0; r < 4; r++) {
        u32 d0 = pk2(__builtin_amdgcn_exp2f(s[0][r]), __builtin_amdgcn_exp2f(s[1][r]));
        u32 d1 = pk2(__builtin_amdgcn_exp2f(s[2][r]), __builtin_amdgcn_exp2f(s[3][r]));
        u32* dst = (u32*)&sPw[(i * 16 + quad * 4 + r) * 72 + l16 * 4];
        dst[0] = d0;
        dst[1] = d1;
      }
    }
    // O += P V
#pragma unroll
    for (int ks = 0; ks < 2; ks++) {
      bf16x8 bv[3];
#pragma unroll
      for (int j = 0; j < 3; j++) {
        int d = j * 16 + l16;
        bv[j] = *(const bf16x8*)&sV[d * 64 + (((ks * 4 + quad) ^ (d & 7)) * 8)];
      }
#pragma unroll
      for (int i = 0; i < 2; i++) {
        bf16x8 ap = *(const bf16x8*)&sPw[(i * 16 + l16) * 72 + ks * 32 + quad * 8];
#pragma unroll
        for (int j = 0; j < 3; j++)
          o[i][j] = __builtin_amdgcn_mfma_f32_16x16x32_bf16(ap, bv[j], o[i][j], 0, 0, 0);
      }
    }
  }

  // epilogue: row-sum = col 42 of o[i][2] (lane quad*16+10); intra-wave shuffle broadcast
  const int b = bh / NH, h = bh - b * NH;
#pragma unroll
  for (int i = 0; i < 2; i++) {
#pragma unroll
    for (int r = 0; r < 4; r++) {
      float ls = __shfl(o[i][2][r], (lane & 48) + 10, 64);
      float rc = 1.f / ls;
      int row = wave * 32 + i * 16 + quad * 4 + r;
      float* orow = out + ((size_t)(b * SEQ + q0 + row)) * CC + h * HD;
#pragma unroll
      for (int j = 0; j < 3; j++) {
        int d = j * 16 + l16;
        if (d < HD) orow[d] = o[i][j][r] * rc;
      }
    }
  }
}

extern "C" void kernel_launch(void* const* d_in, const int* in_sizes, int n_in,
                              void* d_out, int out_size, void* d_ws, size_t ws_size,
                              hipStream_t stream) {
  (void)in_sizes; (void)n_in; (void)out_size; (void)ws_size;
  const float* x      = (const float*)d_in[0];
  const float* conv_w = (const float*)d_in[1];
  const float* conv_b = (const float*)d_in[2];
  const float* qkv_w  = (const float*)d_in[3];
  const float* qkv_b  = (const float*)d_in[4];
  float* out = (float*)d_out;

  char* ws = (char*)d_ws;
  size_t off = 0;
  u16* A      = (u16*)(ws + off); off += (size_t)MTOK * KP * 2;       // 10.5 MB
  u16* Wc     = (u16*)(ws + off); off += (size_t)640 * KP * 2;        // 0.8 MB
  u16* Wq     = (u16*)(ws + off); off += (size_t)1792 * KP * 2;       // 2.3 MB
  u16* tokens = (u16*)(ws + off); off += (size_t)MTOK * KP * 2;       // 10.5 MB
  u16* qbuf   = (u16*)(ws + off); off += (size_t)112 * SEQ * DP * 2;  // 14.7 MB
  u16* kbuf   = (u16*)(ws + off); off += (size_t)112 * SEQ * DP * 2;  // 14.7 MB
  u16* vTb    = (u16*)(ws + off); off += (size_t)112 * DV * SEQ * 2;  // 11.0 MB

  prep_k<<<MTOK + 2432, 256, 0, stream>>>(x, A, vTb, qbuf, kbuf, conv_w, qkv_w, Wc, Wq);
  gemm_k<0><<<dim3(64, 5), 256, 0, stream>>>(A, Wc, conv_b, tokens, nullptr, nullptr, nullptr);
  gemm_k<1><<<dim3(64, 14), 256, 0, stream>>>(tokens, Wq, qkv_b, nullptr, qbuf, kbuf, vTb);
  attn_k<<<896, 256, 0, stream>>>(qbuf, kbuf, vTb, out);
}